// Round 4
// baseline (758.415 us; speedup 1.0000x reference)
//
#include <hip/hip_runtime.h>
#include <hip/hip_bf16.h>

#define BB 128
#define LC 256
#define LE 1024
#define DD 256
#define MM 512

typedef short bf16x8 __attribute__((ext_vector_type(8)));
typedef unsigned short u16x8 __attribute__((ext_vector_type(8)));
typedef float f32x4 __attribute__((ext_vector_type(4)));

__device__ __forceinline__ float bfu2f(unsigned short u) {
  return __uint_as_float(((unsigned int)u) << 16);
}
__device__ __forceinline__ unsigned short f2bfu(float f) {
  unsigned int x = __float_as_uint(f);
  return (unsigned short)((x + 0x7fffu + ((x >> 16) & 1u)) >> 16);
}

// LDS tile: 128 rows x 32 k (u16), row stride 40, 16B-chunk XOR swizzle.
#define LDST 40
__device__ __forceinline__ int ldsoff(int r, int q) {
  return r * LDST + ((q ^ ((r >> 2) & 3)) << 3);
}

// ---- shared MFMA inner step: 4 waves, each 64x64 = 4x4 tiles of 16x16x32 ----
__device__ __forceinline__ void mma_step(const unsigned short* As, const unsigned short* Bs,
                                         f32x4 (&acc)[4][4], int wm, int wn, int lane) {
  const int lm = lane & 15, quad = lane >> 4;
  bf16x8 a[4], b[4];
#pragma unroll
  for (int i = 0; i < 4; ++i) {
    int r = wm * 64 + i * 16 + lm;
    a[i] = *(const bf16x8*)&As[ldsoff(r, quad)];
    int n = wn * 64 + i * 16 + lm;
    b[i] = *(const bf16x8*)&Bs[ldsoff(n, quad)];
  }
#pragma unroll
  for (int i = 0; i < 4; ++i)
#pragma unroll
    for (int j = 0; j < 4; ++j)
      acc[i][j] = __builtin_amdgcn_mfma_f32_16x16x32_bf16(a[i], b[j], acc[i][j], 0, 0, 0);
}

// ---- natural staging: bf16 source rows [r][k], 128x32 tile ----
__device__ __forceinline__ void stage_bf16(unsigned short* S, const unsigned short* g,
                                           long ld, int tid) {
#pragma unroll
  for (int i = 0; i < 2; ++i) {
    int c = tid + i * 256;
    int r = c >> 2, q = c & 3;
    u16x8 v = *(const u16x8*)(g + (long)r * ld + q * 8);
    *(u16x8*)&S[ldsoff(r, q)] = v;
  }
}

// ---- natural staging with fp32 -> bf16 convert ----
__device__ __forceinline__ void stage_f32(unsigned short* S, const float* g, long ld, int tid) {
#pragma unroll
  for (int i = 0; i < 2; ++i) {
    int c = tid + i * 256;
    int r = c >> 2, q = c & 3;
    const float4* p = (const float4*)(g + (long)r * ld + q * 8);
    float4 v0 = p[0], v1 = p[1];
    u16x8 o;
    o[0] = f2bfu(v0.x); o[1] = f2bfu(v0.y); o[2] = f2bfu(v0.z); o[3] = f2bfu(v0.w);
    o[4] = f2bfu(v1.x); o[5] = f2bfu(v1.y); o[6] = f2bfu(v1.z); o[7] = f2bfu(v1.w);
    *(u16x8*)&S[ldsoff(r, q)] = o;
  }
}

// ---- zero fill ----
__global__ void zero_kernel(float* __restrict__ p, int n) {
  int i = blockIdx.x * 256 + threadIdx.x;
  if (i < n) p[i] = 0.f;
}

// ---- weight transpose+convert: WaT[n][k]=Wa[k][n], WrT[n][k]=Wr[k][n] ----
__global__ void wconv_kernel(const float* __restrict__ Wa, const float* __restrict__ Wr,
                             unsigned short* __restrict__ WaT, unsigned short* __restrict__ WrT) {
  int i = blockIdx.x * 256 + threadIdx.x;
  if (i < 65536) WaT[i] = f2bfu(Wa[(i & 255) * 256 + (i >> 8)]);
  if (i < 131072) WrT[i] = f2bfu(Wr[(long)(i & 511) * 256 + (i >> 9)]);
}

// ---- generic fp32 [R][C] -> bf16 transposed [C][R], per batch, 64x64 tiles ----
__global__ void transT_kernel(const float* __restrict__ src, unsigned short* __restrict__ dst,
                              int R, int C) {
  __shared__ unsigned short T[64][72];
  const int tid = threadIdx.x, b = blockIdx.z;
  const int r0 = blockIdx.y * 64, c0 = blockIdx.x * 64;
  const float* s = src + (long)b * R * C;
  unsigned short* d = dst + (long)b * R * C;
#pragma unroll
  for (int i = 0; i < 4; ++i) {
    int r = (tid >> 4) + i * 16, c4 = tid & 15;
    float4 v = *(const float4*)(s + (long)(r0 + r) * C + c0 + c4 * 4);
    T[c4 * 4 + 0][r] = f2bfu(v.x);
    T[c4 * 4 + 1][r] = f2bfu(v.y);
    T[c4 * 4 + 2][r] = f2bfu(v.z);
    T[c4 * 4 + 3][r] = f2bfu(v.w);
  }
  __syncthreads();
#pragma unroll
  for (int j = 0; j < 2; ++j) {
    int idx = tid * 2 + j;
    int row = idx >> 3, ch = idx & 7;
    *(u16x8*)(d + (long)(c0 + row) * R + r0 + ch * 8) = *(const u16x8*)&T[row][ch * 8];
  }
}

// ---- proj: out = relu(A @ Wa + ba) -> bf16 ----
__global__ __launch_bounds__(256, 2) void proj_mfma(const float* __restrict__ A,
                                                    const unsigned short* __restrict__ WaT,
                                                    const float* __restrict__ ba,
                                                    unsigned short* __restrict__ out) {
  __shared__ unsigned short As[128 * LDST], Bs[128 * LDST];
  const int tid = threadIdx.x, lane = tid & 63, w = tid >> 6, wm = w >> 1, wn = w & 1;
  const long m0 = (long)blockIdx.y * 128;
  const int n0 = blockIdx.x * 128;
  f32x4 acc[4][4] = {};
  for (int k0 = 0; k0 < DD; k0 += 32) {
    stage_f32(As, A + m0 * DD + k0, DD, tid);
    stage_bf16(Bs, WaT + (long)n0 * DD + k0, DD, tid);
    __syncthreads();
    mma_step(As, Bs, acc, wm, wn, lane);
    __syncthreads();
  }
  const int lm = lane & 15, quad = lane >> 4;
#pragma unroll
  for (int i = 0; i < 4; ++i)
#pragma unroll
    for (int j = 0; j < 4; ++j) {
      int col = n0 + wn * 64 + j * 16 + lm;
      float bias = ba[col];
#pragma unroll
      for (int r = 0; r < 4; ++r) {
        long row = m0 + wm * 64 + i * 16 + quad * 4 + r;
        float v = acc[i][j][r] + bias;
        out[row * DD + col] = f2bfu(v > 0.f ? v : 0.f);
      }
    }
}

// ---- align[b,l,e] = c[b,l,:] . e[b,e,:] ----
__global__ __launch_bounds__(256, 2) void align_mfma(const unsigned short* __restrict__ cB,
                                                     const unsigned short* __restrict__ eB,
                                                     unsigned short* __restrict__ alignB) {
  __shared__ unsigned short As[128 * LDST], Bs[128 * LDST];
  const int tid = threadIdx.x, lane = tid & 63, w = tid >> 6, wm = w >> 1, wn = w & 1;
  const int b = blockIdx.z, m0 = blockIdx.y * 128, n0 = blockIdx.x * 128;
  const unsigned short* Ag = cB + ((long)b * LC + m0) * DD;
  const unsigned short* Bg = eB + ((long)b * LE + n0) * DD;
  f32x4 acc[4][4] = {};
  for (int k0 = 0; k0 < DD; k0 += 32) {
    stage_bf16(As, Ag + k0, DD, tid);
    stage_bf16(Bs, Bg + k0, DD, tid);
    __syncthreads();
    mma_step(As, Bs, acc, wm, wn, lane);
    __syncthreads();
  }
  const int lm = lane & 15, quad = lane >> 4;
#pragma unroll
  for (int i = 0; i < 4; ++i)
#pragma unroll
    for (int j = 0; j < 4; ++j) {
      int col = n0 + wn * 64 + j * 16 + lm;
#pragma unroll
      for (int r = 0; r < 4; ++r) {
        int row = m0 + wm * 64 + i * 16 + quad * 4 + r;
        alignB[((long)b * LC + row) * LE + col] = f2bfu(acc[i][j][r]);
      }
    }
}

// ---- alpha stats ----
__global__ void astats_kernel(const unsigned short* __restrict__ alignB,
                              const int* __restrict__ em,
                              float* __restrict__ amax, float* __restrict__ asum) {
  const int b = blockIdx.y, l = blockIdx.x, tid = threadIdx.x;
  const unsigned short* row = alignB + ((size_t)b * LC + l) * LE;
  const int* emb = em + b * LE;
  float vals[4];
  float m = -1e30f;
#pragma unroll
  for (int i = 0; i < 4; ++i) {
    int e = tid + i * 256;
    float v = bfu2f(row[e]) + (emb[e] ? 0.f : -1e9f);
    vals[i] = v;
    m = fmaxf(m, v);
  }
  __shared__ float red[256];
  red[tid] = m; __syncthreads();
  for (int s = 128; s > 0; s >>= 1) {
    if (tid < s) red[tid] = fmaxf(red[tid], red[tid + s]);
    __syncthreads();
  }
  m = red[0];
  __syncthreads();
  float s = 0.f;
#pragma unroll
  for (int i = 0; i < 4; ++i) s += __expf(vals[i] - m);
  red[tid] = s; __syncthreads();
  for (int st = 128; st > 0; st >>= 1) {
    if (tid < st) red[tid] += red[tid + st];
    __syncthreads();
  }
  if (tid == 0) { amax[b * LC + l] = m; asum[b * LC + l] = red[0]; }
}

// ---- beta stats ----
__global__ void bstats_kernel(const unsigned short* __restrict__ alignB,
                              const int* __restrict__ cm,
                              float* __restrict__ bmax, float* __restrict__ bsum) {
  const int b = blockIdx.y;
  const int e = blockIdx.x * 256 + threadIdx.x;
  const int* cmb = cm + b * LC;
  float m = -1e30f, s = 0.f;
  for (int l = 0; l < LC; ++l) {
    float v = bfu2f(alignB[((size_t)b * LC + l) * LE + e]) + (cmb[l] ? 0.f : -1e9f);
    if (v > m) { s = s * __expf(m - v) + 1.f; m = v; }
    else s += __expf(v - m);
  }
  bmax[b * LE + e] = m;
  bsum[b * LE + e] = s;
}

// ---- betask: betaT[b][e][l] = softmax-col transform of alignB, 64x64 tile transpose ----
// MUST run before alphask (reads original align values).
__global__ void betask_kernel(const unsigned short* __restrict__ alignB,
                              const int* __restrict__ cm,
                              const float* __restrict__ bmax, const float* __restrict__ bsum,
                              unsigned short* __restrict__ betaT) {
  __shared__ unsigned short T[64][72];
  const int tid = threadIdx.x, b = blockIdx.z;
  const int l0 = blockIdx.y * 64, e0 = blockIdx.x * 64;
#pragma unroll
  for (int i = 0; i < 2; ++i) {
    int r = (tid >> 3) + i * 32, ch = tid & 7;
    int gl = l0 + r;
    float msk = cm[b * LC + gl] ? 0.f : -1e9f;
    u16x8 v = *(const u16x8*)&alignB[((long)b * LC + gl) * LE + e0 + ch * 8];
    int ebase = b * LE + e0 + ch * 8;
    float4 xa = *(const float4*)&bmax[ebase];
    float4 xb = *(const float4*)&bmax[ebase + 4];
    float4 sa = *(const float4*)&bsum[ebase];
    float4 sb = *(const float4*)&bsum[ebase + 4];
    float mx[8] = {xa.x, xa.y, xa.z, xa.w, xb.x, xb.y, xb.z, xb.w};
    float sm[8] = {sa.x, sa.y, sa.z, sa.w, sb.x, sb.y, sb.z, sb.w};
#pragma unroll
    for (int k = 0; k < 8; ++k)
      T[ch * 8 + k][r] = f2bfu(__expf(bfu2f(v[k]) + msk - mx[k]) * (1.f / sm[k]));
  }
  __syncthreads();
#pragma unroll
  for (int j = 0; j < 2; ++j) {
    int idx = tid * 2 + j;
    int row = idx >> 3, ch = idx & 7;
    *(u16x8*)(betaT + ((long)b * LE + e0 + row) * LC + l0 + ch * 8) =
        *(const u16x8*)&T[row][ch * 8];
  }
}

// ---- alphask: in-place alpha softmax over alignB ----
__global__ void alphask_kernel(unsigned short* __restrict__ alignB,
                               const int* __restrict__ em,
                               const float* __restrict__ amax, const float* __restrict__ asum) {
  int idx = blockIdx.x * 256 + threadIdx.x;  // 4,194,304 chunks of 8
  int e8 = idx & 127;       // LE/8 = 128
  int row = idx >> 7;       // b*LC + l
  int b = row >> 8;
  float mx = amax[row];
  float rs = 1.f / asum[row];
  unsigned short* p = alignB + (long)row * LE + e8 * 8;
  u16x8 v = *(const u16x8*)p;
  int eb = b * LE + e8 * 8;
  int4 ma = *(const int4*)&em[eb];
  int4 mb = *(const int4*)&em[eb + 4];
  int mk[8] = {ma.x, ma.y, ma.z, ma.w, mb.x, mb.y, mb.z, mb.w};
  u16x8 o;
#pragma unroll
  for (int k = 0; k < 8; ++k)
    o[k] = f2bfu(__expf(bfu2f(v[k]) + (mk[k] ? 0.f : -1e9f) - mx) * rs);
  *(u16x8*)p = o;
}

// ---- attc = alphaB @ ehrT^T (pure bf16 GEMM) ----
__global__ __launch_bounds__(256, 2) void attc_mfma(const unsigned short* __restrict__ alphaB,
                                                    const unsigned short* __restrict__ ehrT,
                                                    unsigned short* __restrict__ attc) {
  __shared__ unsigned short As[128 * LDST], Bs[128 * LDST];
  const int tid = threadIdx.x, lane = tid & 63, w = tid >> 6, wm = w >> 1, wn = w & 1;
  const int b = blockIdx.z, m0 = blockIdx.y * 128, n0 = blockIdx.x * 128;
  const unsigned short* Ag = alphaB + ((long)b * LC + m0) * LE;
  const unsigned short* Bg = ehrT + ((long)b * DD + n0) * LE;
  f32x4 acc[4][4] = {};
  for (int k0 = 0; k0 < LE; k0 += 32) {
    stage_bf16(As, Ag + k0, LE, tid);
    stage_bf16(Bs, Bg + k0, LE, tid);
    __syncthreads();
    mma_step(As, Bs, acc, wm, wn, lane);
    __syncthreads();
  }
  const int lm = lane & 15, quad = lane >> 4;
#pragma unroll
  for (int i = 0; i < 4; ++i)
#pragma unroll
    for (int j = 0; j < 4; ++j) {
      int col = n0 + wn * 64 + j * 16 + lm;
#pragma unroll
      for (int r = 0; r < 4; ++r) {
        int row = m0 + wm * 64 + i * 16 + quad * 4 + r;
        attc[((long)b * LC + row) * DD + col] = f2bfu(acc[i][j][r]);
      }
    }
}

// ---- atte = betaT @ critT^T (pure bf16 GEMM) ----
__global__ __launch_bounds__(256, 2) void atte_mfma(const unsigned short* __restrict__ betaT,
                                                    const unsigned short* __restrict__ critT,
                                                    unsigned short* __restrict__ atte) {
  __shared__ unsigned short As[128 * LDST], Bs[128 * LDST];
  const int tid = threadIdx.x, lane = tid & 63, w = tid >> 6, wm = w >> 1, wn = w & 1;
  const int b = blockIdx.z, m0 = blockIdx.y * 128, n0 = blockIdx.x * 128;
  const unsigned short* Ag = betaT + ((long)b * LE + m0) * LC;
  const unsigned short* Bg = critT + ((long)b * DD + n0) * LC;
  f32x4 acc[4][4] = {};
  for (int k0 = 0; k0 < LC; k0 += 32) {
    stage_bf16(As, Ag + k0, LC, tid);
    stage_bf16(Bs, Bg + k0, LC, tid);
    __syncthreads();
    mma_step(As, Bs, acc, wm, wn, lane);
    __syncthreads();
  }
  const int lm = lane & 15, quad = lane >> 4;
#pragma unroll
  for (int i = 0; i < 4; ++i)
#pragma unroll
    for (int j = 0; j < 4; ++j) {
      int col = n0 + wn * 64 + j * 16 + lm;
#pragma unroll
      for (int r = 0; r < 4; ++r) {
        int row = m0 + wm * 64 + i * 16 + quad * 4 + r;
        atte[((long)b * LE + row) * DD + col] = f2bfu(acc[i][j][r]);
      }
    }
}

// ---- r = sum_seq relu([att | orig] @ Wr + br) ----
__global__ __launch_bounds__(256, 2) void rsum_mfma(const unsigned short* __restrict__ att,
                                                    const float* __restrict__ orig,
                                                    const unsigned short* __restrict__ WrT,
                                                    const float* __restrict__ br,
                                                    float* __restrict__ rout, int Lseq) {
  __shared__ unsigned short As[128 * LDST], Bs[128 * LDST];
  __shared__ float red[2][128];
  const int tid = threadIdx.x, lane = tid & 63, w = tid >> 6, wm = w >> 1, wn = w & 1;
  const long m0 = (long)blockIdx.y * 128;
  const int n0 = blockIdx.x * 128;
  const int b = (int)(m0 / Lseq);
  f32x4 acc[4][4] = {};
  for (int k0 = 0; k0 < 2 * DD; k0 += 32) {
    if (k0 < DD)
      stage_bf16(As, att + m0 * DD + k0, DD, tid);
    else
      stage_f32(As, orig + m0 * DD + (k0 - DD), DD, tid);
    stage_bf16(Bs, WrT + (long)n0 * (2 * DD) + k0, 2 * DD, tid);
    __syncthreads();
    mma_step(As, Bs, acc, wm, wn, lane);
    __syncthreads();
  }
  const int lm = lane & 15, quad = lane >> 4;
#pragma unroll
  for (int j = 0; j < 4; ++j) {
    int col = n0 + wn * 64 + j * 16 + lm;
    float bias = br[col];
    float s = 0.f;
#pragma unroll
    for (int i = 0; i < 4; ++i)
#pragma unroll
      for (int r = 0; r < 4; ++r) {
        float v = acc[i][j][r] + bias;
        s += v > 0.f ? v : 0.f;
      }
    s += __shfl_xor(s, 16);
    s += __shfl_xor(s, 32);
    if (quad == 0) red[wm][wn * 64 + j * 16 + lm] = s;
  }
  __syncthreads();
  if (tid < 128)
    atomicAdd(&rout[b * DD + n0 + tid], red[0][tid] + red[1][tid]);
}

// ---- build m = [r1 | r2 | r1*r2 | r1-r2] as bf16 [128][1024] ----
__global__ void mbuild_kernel(const float* __restrict__ r1, const float* __restrict__ r2,
                              unsigned short* __restrict__ mB) {
  int i = blockIdx.x * 256 + threadIdx.x;
  int b = i >> 8, d = i & 255;
  float v1 = r1[i], v2 = r2[i];
  unsigned short* row = mB + (long)b * 1024;
  row[d] = f2bfu(v1);
  row[256 + d] = f2bfu(v2);
  row[512 + d] = f2bfu(v1 * v2);
  row[768 + d] = f2bfu(v1 - v2);
}

// ---- h = relu(m @ Wm + bm): M=128, N=512, K=1024 MFMA GEMM ----
__global__ __launch_bounds__(256, 2) void mlp_mfma(const unsigned short* __restrict__ mB,
                                                   const float* __restrict__ Wm,
                                                   const float* __restrict__ bm,
                                                   float* __restrict__ h) {
  __shared__ unsigned short As[128 * LDST], Bs[128 * LDST];
  const int tid = threadIdx.x, lane = tid & 63, w = tid >> 6, wm = w >> 1, wn = w & 1;
  const int n0 = blockIdx.x * 128;
  f32x4 acc[4][4] = {};
  for (int k0 = 0; k0 < 4 * DD; k0 += 32) {
    stage_bf16(As, mB + k0, 4 * DD, tid);
    // B: Wm^T scatter (tiny kernel, keep simple)
    {
      const int dcc = tid & 7, er = tid >> 3;
#pragma unroll
      for (int i = 0; i < 4; ++i) {
        int nch = dcc + i * 8;
        float4 v = *(const float4*)(Wm + (long)(k0 + er) * MM + n0 + nch * 4);
        float vv[4] = {v.x, v.y, v.z, v.w};
#pragma unroll
        for (int q = 0; q < 4; ++q)
          Bs[ldsoff(nch * 4 + q, er >> 3) + (er & 7)] = f2bfu(vv[q]);
      }
    }
    __syncthreads();
    mma_step(As, Bs, acc, wm, wn, lane);
    __syncthreads();
  }
  const int lm = lane & 15, quad = lane >> 4;
#pragma unroll
  for (int i = 0; i < 4; ++i)
#pragma unroll
    for (int j = 0; j < 4; ++j) {
      int col = n0 + wn * 64 + j * 16 + lm;
      float bias = bm[col];
#pragma unroll
      for (int r = 0; r < 4; ++r) {
        int row = wm * 64 + i * 16 + quad * 4 + r;
        float v = acc[i][j][r] + bias;
        h[(long)row * MM + col] = v > 0.f ? v : 0.f;
      }
    }
}

// ---- out = h @ Wo + bo ----
__global__ void out3_kernel(const float* __restrict__ h, const float* __restrict__ Wo,
                            const float* __restrict__ bo, float* __restrict__ out) {
  const int b = blockIdx.x, tid = threadIdx.x;
  __shared__ float red[256];
  float a[3] = {0.f, 0.f, 0.f};
  for (int k = tid; k < MM; k += 256) {
    float hv = h[(long)b * MM + k];
    a[0] += hv * Wo[k * 3 + 0];
    a[1] += hv * Wo[k * 3 + 1];
    a[2] += hv * Wo[k * 3 + 2];
  }
#pragma unroll
  for (int o = 0; o < 3; ++o) {
    red[tid] = a[o]; __syncthreads();
    for (int st = 128; st > 0; st >>= 1) {
      if (tid < st) red[tid] += red[tid + st];
      __syncthreads();
    }
    if (tid == 0) out[b * 3 + o] = red[0] + bo[o];
    __syncthreads();
  }
}

extern "C" void kernel_launch(void* const* d_in, const int* in_sizes, int n_in,
                              void* d_out, int out_size, void* d_ws, size_t ws_size,
                              hipStream_t stream) {
  const float* criteria = (const float*)d_in[0];
  const float* ehr      = (const float*)d_in[1];
  const int*   cmask    = (const int*)d_in[2];
  const int*   emask    = (const int*)d_in[3];
  const float* Wa       = (const float*)d_in[4];
  const float* ba       = (const float*)d_in[5];
  const float* Wr       = (const float*)d_in[6];
  const float* br       = (const float*)d_in[7];
  const float* Wm       = (const float*)d_in[8];
  const float* bm       = (const float*)d_in[9];
  const float* Wo       = (const float*)d_in[10];
  const float* bo       = (const float*)d_in[11];
  float* out = (float*)d_out;

  char* ws = (char*)d_ws;
  // Buffer choreography (237.4 MB total):
  //   cB [0,16.78M)        : c projections -> attc output (dead after align)
  //   eB [16.78M,83.89M)   : e projections -> betaT (dead after align)
  //   alignB [83.89M,151M) : align -> alphaB in place -> atte output (dead after attc)
  //   ehrT [151M,218.1M)   : bf16 ehr^T [b][d][e]
  //   critT [218.1M,234.9M): bf16 criteria^T [b][d][l]
  unsigned short* cB     = (unsigned short*)(ws);
  unsigned short* eB     = (unsigned short*)(ws + 16777216);
  unsigned short* alignB = (unsigned short*)(ws + 83886080);
  unsigned short* ehrT   = (unsigned short*)(ws + 150994944);
  unsigned short* critT  = (unsigned short*)(ws + 218103808);
  float* amax = (float*)(ws + 234881024);
  float* asum = (float*)(ws + 235012096);
  float* bmax = (float*)(ws + 235143168);
  float* bsum = (float*)(ws + 235667456);
  float* r1   = (float*)(ws + 236191744);
  float* r2   = (float*)(ws + 236322816);
  unsigned short* WaT = (unsigned short*)(ws + 236453888);
  unsigned short* WrT = (unsigned short*)(ws + 236584960);
  unsigned short* mB  = (unsigned short*)(ws + 236847104);
  float* hbuf         = (float*)(ws + 237109248);
  // end: 237,371,392 bytes
  unsigned short* betaT = eB;       // reuse after align
  unsigned short* attc  = cB;       // reuse after align
  unsigned short* atteP = alignB;   // reuse after attc

  dim3 blk(256);
  zero_kernel<<<dim3(256), blk, 0, stream>>>(r1, 2 * BB * DD);
  wconv_kernel<<<dim3(512), blk, 0, stream>>>(Wa, Wr, WaT, WrT);
  transT_kernel<<<dim3(DD / 64, LE / 64, BB), blk, 0, stream>>>(ehr, ehrT, LE, DD);
  transT_kernel<<<dim3(DD / 64, LC / 64, BB), blk, 0, stream>>>(criteria, critT, LC, DD);
  proj_mfma<<<dim3(2, (BB * LC) / 128), blk, 0, stream>>>(criteria, WaT, ba, cB);
  proj_mfma<<<dim3(2, (BB * LE) / 128), blk, 0, stream>>>(ehr, WaT, ba, eB);
  align_mfma<<<dim3(LE / 128, LC / 128, BB), blk, 0, stream>>>(cB, eB, alignB);
  astats_kernel<<<dim3(LC, BB), blk, 0, stream>>>(alignB, emask, amax, asum);
  bstats_kernel<<<dim3(LE / 256, BB), blk, 0, stream>>>(alignB, cmask, bmax, bsum);
  betask_kernel<<<dim3(LE / 64, LC / 64, BB), blk, 0, stream>>>(alignB, cmask, bmax, bsum, betaT);
  alphask_kernel<<<dim3(16384), blk, 0, stream>>>(alignB, emask, amax, asum);
  attc_mfma<<<dim3(DD / 128, LC / 128, BB), blk, 0, stream>>>(alignB, ehrT, attc);
  atte_mfma<<<dim3(DD / 128, LE / 128, BB), blk, 0, stream>>>(betaT, critT, atteP);
  rsum_mfma<<<dim3(2, (BB * LC) / 128), blk, 0, stream>>>(attc, criteria, WrT, br, r1, LC);
  rsum_mfma<<<dim3(2, (BB * LE) / 128), blk, 0, stream>>>(atteP, ehr, WrT, br, r2, LE);
  mbuild_kernel<<<dim3(BB), blk, 0, stream>>>(r1, r2, mB);
  mlp_mfma<<<dim3(MM / 128), blk, 0, stream>>>(mB, Wm, bm, hbuf);
  out3_kernel<<<dim3(BB), blk, 0, stream>>>(hbuf, Wo, bo, out);
}

// Round 5
// 678.605 us; speedup vs baseline: 1.1176x; 1.1176x over previous
//
#include <hip/hip_runtime.h>
#include <hip/hip_bf16.h>

#define BB 128
#define LC 256
#define LE 1024
#define DD 256
#define MM 512

typedef short bf16x8 __attribute__((ext_vector_type(8)));
typedef unsigned short u16x8 __attribute__((ext_vector_type(8)));
typedef float f32x4 __attribute__((ext_vector_type(4)));

__device__ __forceinline__ float bfu2f(unsigned short u) {
  return __uint_as_float(((unsigned int)u) << 16);
}
__device__ __forceinline__ unsigned short f2bfu(float f) {
  unsigned int x = __float_as_uint(f);
  return (unsigned short)((x + 0x7fffu + ((x >> 16) & 1u)) >> 16);
}

// LDS tile: 128 rows x 32 k (u16), row stride 40, 16B-chunk XOR swizzle.
#define LDST 40
__device__ __forceinline__ int ldsoff(int r, int q) {
  return r * LDST + ((q ^ ((r >> 2) & 3)) << 3);
}

// ---- shared MFMA inner step: 4 waves, each 64x64 = 4x4 tiles of 16x16x32 ----
__device__ __forceinline__ void mma_step(const unsigned short* As, const unsigned short* Bs,
                                         f32x4 (&acc)[4][4], int wm, int wn, int lane) {
  const int lm = lane & 15, quad = lane >> 4;
  bf16x8 a[4], b[4];
#pragma unroll
  for (int i = 0; i < 4; ++i) {
    int r = wm * 64 + i * 16 + lm;
    a[i] = *(const bf16x8*)&As[ldsoff(r, quad)];
    int n = wn * 64 + i * 16 + lm;
    b[i] = *(const bf16x8*)&Bs[ldsoff(n, quad)];
  }
#pragma unroll
  for (int i = 0; i < 4; ++i)
#pragma unroll
    for (int j = 0; j < 4; ++j)
      acc[i][j] = __builtin_amdgcn_mfma_f32_16x16x32_bf16(a[i], b[j], acc[i][j], 0, 0, 0);
}

// ---- natural staging: bf16 source rows [r][k], 128x32 tile ----
__device__ __forceinline__ void stage_bf16(unsigned short* S, const unsigned short* g,
                                           long ld, int tid) {
#pragma unroll
  for (int i = 0; i < 2; ++i) {
    int c = tid + i * 256;
    int r = c >> 2, q = c & 3;
    u16x8 v = *(const u16x8*)(g + (long)r * ld + q * 8);
    *(u16x8*)&S[ldsoff(r, q)] = v;
  }
}

// ---- natural staging with fp32 -> bf16 convert ----
__device__ __forceinline__ void stage_f32(unsigned short* S, const float* g, long ld, int tid) {
#pragma unroll
  for (int i = 0; i < 2; ++i) {
    int c = tid + i * 256;
    int r = c >> 2, q = c & 3;
    const float4* p = (const float4*)(g + (long)r * ld + q * 8);
    float4 v0 = p[0], v1 = p[1];
    u16x8 o;
    o[0] = f2bfu(v0.x); o[1] = f2bfu(v0.y); o[2] = f2bfu(v0.z); o[3] = f2bfu(v0.w);
    o[4] = f2bfu(v1.x); o[5] = f2bfu(v1.y); o[6] = f2bfu(v1.z); o[7] = f2bfu(v1.w);
    *(u16x8*)&S[ldsoff(r, q)] = o;
  }
}

// ---- zero fill ----
__global__ void zero_kernel(float* __restrict__ p, int n) {
  int i = blockIdx.x * 256 + threadIdx.x;
  if (i < n) p[i] = 0.f;
}

// ---- weight transpose+convert ----
__global__ void wconv_kernel(const float* __restrict__ Wa, const float* __restrict__ Wr,
                             unsigned short* __restrict__ WaT, unsigned short* __restrict__ WrT) {
  int i = blockIdx.x * 256 + threadIdx.x;
  if (i < 65536) WaT[i] = f2bfu(Wa[(i & 255) * 256 + (i >> 8)]);
  if (i < 131072) WrT[i] = f2bfu(Wr[(long)(i & 511) * 256 + (i >> 9)]);
}

// ---- generic fp32 [R][C] -> bf16 transposed [C][R], per batch, 64x64 tiles ----
__global__ void transT_kernel(const float* __restrict__ src, unsigned short* __restrict__ dst,
                              int R, int C) {
  __shared__ unsigned short T[64][72];
  const int tid = threadIdx.x, b = blockIdx.z;
  const int r0 = blockIdx.y * 64, c0 = blockIdx.x * 64;
  const float* s = src + (long)b * R * C;
  unsigned short* d = dst + (long)b * R * C;
#pragma unroll
  for (int i = 0; i < 4; ++i) {
    int r = (tid >> 4) + i * 16, c4 = tid & 15;
    float4 v = *(const float4*)(s + (long)(r0 + r) * C + c0 + c4 * 4);
    T[c4 * 4 + 0][r] = f2bfu(v.x);
    T[c4 * 4 + 1][r] = f2bfu(v.y);
    T[c4 * 4 + 2][r] = f2bfu(v.z);
    T[c4 * 4 + 3][r] = f2bfu(v.w);
  }
  __syncthreads();
#pragma unroll
  for (int j = 0; j < 2; ++j) {
    int idx = tid * 2 + j;
    int row = idx >> 3, ch = idx & 7;
    *(u16x8*)(d + (long)(c0 + row) * R + r0 + ch * 8) = *(const u16x8*)&T[row][ch * 8];
  }
}

// ---- proj: out = relu(A @ Wa + ba) -> bf16 ----
__global__ __launch_bounds__(256, 2) void proj_mfma(const float* __restrict__ A,
                                                    const unsigned short* __restrict__ WaT,
                                                    const float* __restrict__ ba,
                                                    unsigned short* __restrict__ out) {
  __shared__ unsigned short As[128 * LDST], Bs[128 * LDST];
  const int tid = threadIdx.x, lane = tid & 63, w = tid >> 6, wm = w >> 1, wn = w & 1;
  const long m0 = (long)blockIdx.y * 128;
  const int n0 = blockIdx.x * 128;
  f32x4 acc[4][4] = {};
  for (int k0 = 0; k0 < DD; k0 += 32) {
    stage_f32(As, A + m0 * DD + k0, DD, tid);
    stage_bf16(Bs, WaT + (long)n0 * DD + k0, DD, tid);
    __syncthreads();
    mma_step(As, Bs, acc, wm, wn, lane);
    __syncthreads();
  }
  const int lm = lane & 15, quad = lane >> 4;
#pragma unroll
  for (int i = 0; i < 4; ++i)
#pragma unroll
    for (int j = 0; j < 4; ++j) {
      int col = n0 + wn * 64 + j * 16 + lm;
      float bias = ba[col];
#pragma unroll
      for (int r = 0; r < 4; ++r) {
        long row = m0 + wm * 64 + i * 16 + quad * 4 + r;
        float v = acc[i][j][r] + bias;
        out[row * DD + col] = f2bfu(v > 0.f ? v : 0.f);
      }
    }
}

// ---- align[b,l,e] = c[b,l,:] . e[b,e,:] ----
__global__ __launch_bounds__(256, 2) void align_mfma(const unsigned short* __restrict__ cB,
                                                     const unsigned short* __restrict__ eB,
                                                     unsigned short* __restrict__ alignB) {
  __shared__ unsigned short As[128 * LDST], Bs[128 * LDST];
  const int tid = threadIdx.x, lane = tid & 63, w = tid >> 6, wm = w >> 1, wn = w & 1;
  const int b = blockIdx.z, m0 = blockIdx.y * 128, n0 = blockIdx.x * 128;
  const unsigned short* Ag = cB + ((long)b * LC + m0) * DD;
  const unsigned short* Bg = eB + ((long)b * LE + n0) * DD;
  f32x4 acc[4][4] = {};
  for (int k0 = 0; k0 < DD; k0 += 32) {
    stage_bf16(As, Ag + k0, DD, tid);
    stage_bf16(Bs, Bg + k0, DD, tid);
    __syncthreads();
    mma_step(As, Bs, acc, wm, wn, lane);
    __syncthreads();
  }
  const int lm = lane & 15, quad = lane >> 4;
#pragma unroll
  for (int i = 0; i < 4; ++i)
#pragma unroll
    for (int j = 0; j < 4; ++j) {
      int col = n0 + wn * 64 + j * 16 + lm;
#pragma unroll
      for (int r = 0; r < 4; ++r) {
        int row = m0 + wm * 64 + i * 16 + quad * 4 + r;
        alignB[((long)b * LC + row) * LE + col] = f2bfu(acc[i][j][r]);
      }
    }
}

// ---- alpha stats: asum[b,l] = sum_e exp(align + mask), max-free ----
__global__ void astats_kernel(const unsigned short* __restrict__ alignB,
                              const int* __restrict__ em,
                              float* __restrict__ asum) {
  const int b = blockIdx.y, l = blockIdx.x, tid = threadIdx.x;
  const unsigned short* row = alignB + ((size_t)b * LC + l) * LE;
  const int* emb = em + b * LE;
  float s = 0.f;
#pragma unroll
  for (int i = 0; i < 4; ++i) {
    int e = tid + i * 256;
    s += __expf(bfu2f(row[e]) + (emb[e] ? 0.f : -1e9f));
  }
  __shared__ float red[256];
  red[tid] = s; __syncthreads();
  for (int st = 128; st > 0; st >>= 1) {
    if (tid < st) red[tid] += red[tid + st];
    __syncthreads();
  }
  if (tid == 0) asum[b * LC + l] = red[0];
}

// ---- beta stats: bsum[b,e] = sum_l exp(align + mask), max-free (independent exps) ----
__global__ void bstats_kernel(const unsigned short* __restrict__ alignB,
                              const int* __restrict__ cm,
                              float* __restrict__ bsum) {
  const int b = blockIdx.y;
  const int e = blockIdx.x * 256 + threadIdx.x;
  __shared__ float msk[LC];
  for (int l = threadIdx.x; l < LC; l += 256)
    msk[l] = cm[b * LC + l] ? 0.f : -1e9f;
  __syncthreads();
  const unsigned short* p = alignB + (size_t)b * LC * LE + e;
  float s0 = 0.f, s1 = 0.f, s2 = 0.f, s3 = 0.f;
  for (int l = 0; l < LC; l += 4) {
    s0 += __expf(bfu2f(p[(long)(l + 0) * LE]) + msk[l + 0]);
    s1 += __expf(bfu2f(p[(long)(l + 1) * LE]) + msk[l + 1]);
    s2 += __expf(bfu2f(p[(long)(l + 2) * LE]) + msk[l + 2]);
    s3 += __expf(bfu2f(p[(long)(l + 3) * LE]) + msk[l + 3]);
  }
  bsum[b * LE + e] = (s0 + s1) + (s2 + s3);
}

// ---- betask: betaT[b][e][l] bf16, 64x64 tile transpose, max-free ----
// MUST run before alphask (reads original align values).
__global__ void betask_kernel(const unsigned short* __restrict__ alignB,
                              const int* __restrict__ cm,
                              const float* __restrict__ bsum,
                              unsigned short* __restrict__ betaT) {
  __shared__ unsigned short T[64][72];
  const int tid = threadIdx.x, b = blockIdx.z;
  const int l0 = blockIdx.y * 64, e0 = blockIdx.x * 64;
#pragma unroll
  for (int i = 0; i < 2; ++i) {
    int r = (tid >> 3) + i * 32, ch = tid & 7;
    int gl = l0 + r;
    float msk = cm[b * LC + gl] ? 0.f : -1e9f;
    u16x8 v = *(const u16x8*)&alignB[((long)b * LC + gl) * LE + e0 + ch * 8];
    int ebase = b * LE + e0 + ch * 8;
    float4 sa = *(const float4*)&bsum[ebase];
    float4 sb = *(const float4*)&bsum[ebase + 4];
    float sm[8] = {sa.x, sa.y, sa.z, sa.w, sb.x, sb.y, sb.z, sb.w};
#pragma unroll
    for (int k = 0; k < 8; ++k)
      T[ch * 8 + k][r] = f2bfu(__expf(bfu2f(v[k]) + msk) * (1.f / sm[k]));
  }
  __syncthreads();
#pragma unroll
  for (int j = 0; j < 2; ++j) {
    int idx = tid * 2 + j;
    int row = idx >> 3, ch = idx & 7;
    *(u16x8*)(betaT + ((long)b * LE + e0 + row) * LC + l0 + ch * 8) =
        *(const u16x8*)&T[row][ch * 8];
  }
}

// ---- alphask: in-place alpha softmax over alignB, max-free ----
__global__ void alphask_kernel(unsigned short* __restrict__ alignB,
                               const int* __restrict__ em,
                               const float* __restrict__ asum) {
  int idx = blockIdx.x * 256 + threadIdx.x;
  int e8 = idx & 127;       // LE/8 = 128
  int row = idx >> 7;       // b*LC + l
  int b = row >> 8;
  float rs = 1.f / asum[row];
  unsigned short* p = alignB + (long)row * LE + e8 * 8;
  u16x8 v = *(const u16x8*)p;
  int eb = b * LE + e8 * 8;
  int4 ma = *(const int4*)&em[eb];
  int4 mb = *(const int4*)&em[eb + 4];
  int mk[8] = {ma.x, ma.y, ma.z, ma.w, mb.x, mb.y, mb.z, mb.w};
  u16x8 o;
#pragma unroll
  for (int k = 0; k < 8; ++k)
    o[k] = f2bfu(__expf(bfu2f(v[k]) + (mk[k] ? 0.f : -1e9f)) * rs);
  *(u16x8*)p = o;
}

// ---- attc = alphaB @ ehrT^T (pure bf16 GEMM) ----
__global__ __launch_bounds__(256, 2) void attc_mfma(const unsigned short* __restrict__ alphaB,
                                                    const unsigned short* __restrict__ ehrT,
                                                    unsigned short* __restrict__ attc) {
  __shared__ unsigned short As[128 * LDST], Bs[128 * LDST];
  const int tid = threadIdx.x, lane = tid & 63, w = tid >> 6, wm = w >> 1, wn = w & 1;
  const int b = blockIdx.z, m0 = blockIdx.y * 128, n0 = blockIdx.x * 128;
  const unsigned short* Ag = alphaB + ((long)b * LC + m0) * LE;
  const unsigned short* Bg = ehrT + ((long)b * DD + n0) * LE;
  f32x4 acc[4][4] = {};
  for (int k0 = 0; k0 < LE; k0 += 32) {
    stage_bf16(As, Ag + k0, LE, tid);
    stage_bf16(Bs, Bg + k0, LE, tid);
    __syncthreads();
    mma_step(As, Bs, acc, wm, wn, lane);
    __syncthreads();
  }
  const int lm = lane & 15, quad = lane >> 4;
#pragma unroll
  for (int i = 0; i < 4; ++i)
#pragma unroll
    for (int j = 0; j < 4; ++j) {
      int col = n0 + wn * 64 + j * 16 + lm;
#pragma unroll
      for (int r = 0; r < 4; ++r) {
        int row = m0 + wm * 64 + i * 16 + quad * 4 + r;
        attc[((long)b * LC + row) * DD + col] = f2bfu(acc[i][j][r]);
      }
    }
}

// ---- atte = betaT @ critT^T (pure bf16 GEMM) ----
__global__ __launch_bounds__(256, 2) void atte_mfma(const unsigned short* __restrict__ betaT,
                                                    const unsigned short* __restrict__ critT,
                                                    unsigned short* __restrict__ atte) {
  __shared__ unsigned short As[128 * LDST], Bs[128 * LDST];
  const int tid = threadIdx.x, lane = tid & 63, w = tid >> 6, wm = w >> 1, wn = w & 1;
  const int b = blockIdx.z, m0 = blockIdx.y * 128, n0 = blockIdx.x * 128;
  const unsigned short* Ag = betaT + ((long)b * LE + m0) * LC;
  const unsigned short* Bg = critT + ((long)b * DD + n0) * LC;
  f32x4 acc[4][4] = {};
  for (int k0 = 0; k0 < LC; k0 += 32) {
    stage_bf16(As, Ag + k0, LC, tid);
    stage_bf16(Bs, Bg + k0, LC, tid);
    __syncthreads();
    mma_step(As, Bs, acc, wm, wn, lane);
    __syncthreads();
  }
  const int lm = lane & 15, quad = lane >> 4;
#pragma unroll
  for (int i = 0; i < 4; ++i)
#pragma unroll
    for (int j = 0; j < 4; ++j) {
      int col = n0 + wn * 64 + j * 16 + lm;
#pragma unroll
      for (int r = 0; r < 4; ++r) {
        int row = m0 + wm * 64 + i * 16 + quad * 4 + r;
        atte[((long)b * LE + row) * DD + col] = f2bfu(acc[i][j][r]);
      }
    }
}

// ---- r = sum_seq relu([att | orig] @ Wr + br) ----
__global__ __launch_bounds__(256, 2) void rsum_mfma(const unsigned short* __restrict__ att,
                                                    const float* __restrict__ orig,
                                                    const unsigned short* __restrict__ WrT,
                                                    const float* __restrict__ br,
                                                    float* __restrict__ rout, int Lseq) {
  __shared__ unsigned short As[128 * LDST], Bs[128 * LDST];
  __shared__ float red[2][128];
  const int tid = threadIdx.x, lane = tid & 63, w = tid >> 6, wm = w >> 1, wn = w & 1;
  const long m0 = (long)blockIdx.y * 128;
  const int n0 = blockIdx.x * 128;
  const int b = (int)(m0 / Lseq);
  f32x4 acc[4][4] = {};
  for (int k0 = 0; k0 < 2 * DD; k0 += 32) {
    if (k0 < DD)
      stage_bf16(As, att + m0 * DD + k0, DD, tid);
    else
      stage_f32(As, orig + m0 * DD + (k0 - DD), DD, tid);
    stage_bf16(Bs, WrT + (long)n0 * (2 * DD) + k0, 2 * DD, tid);
    __syncthreads();
    mma_step(As, Bs, acc, wm, wn, lane);
    __syncthreads();
  }
  const int lm = lane & 15, quad = lane >> 4;
#pragma unroll
  for (int j = 0; j < 4; ++j) {
    int col = n0 + wn * 64 + j * 16 + lm;
    float bias = br[col];
    float s = 0.f;
#pragma unroll
    for (int i = 0; i < 4; ++i)
#pragma unroll
      for (int r = 0; r < 4; ++r) {
        float v = acc[i][j][r] + bias;
        s += v > 0.f ? v : 0.f;
      }
    s += __shfl_xor(s, 16);
    s += __shfl_xor(s, 32);
    if (quad == 0) red[wm][wn * 64 + j * 16 + lm] = s;
  }
  __syncthreads();
  if (tid < 128)
    atomicAdd(&rout[b * DD + n0 + tid], red[0][tid] + red[1][tid]);
}

// ---- build m = [r1 | r2 | r1*r2 | r1-r2] as bf16 [128][1024] ----
__global__ void mbuild_kernel(const float* __restrict__ r1, const float* __restrict__ r2,
                              unsigned short* __restrict__ mB) {
  int i = blockIdx.x * 256 + threadIdx.x;
  int b = i >> 8, d = i & 255;
  float v1 = r1[i], v2 = r2[i];
  unsigned short* row = mB + (long)b * 1024;
  row[d] = f2bfu(v1);
  row[256 + d] = f2bfu(v2);
  row[512 + d] = f2bfu(v1 * v2);
  row[768 + d] = f2bfu(v1 - v2);
}

// ---- h = relu(m @ Wm + bm): M=128, N=512, K=1024 MFMA GEMM ----
__global__ __launch_bounds__(256, 2) void mlp_mfma(const unsigned short* __restrict__ mB,
                                                   const float* __restrict__ Wm,
                                                   const float* __restrict__ bm,
                                                   float* __restrict__ h) {
  __shared__ unsigned short As[128 * LDST], Bs[128 * LDST];
  const int tid = threadIdx.x, lane = tid & 63, w = tid >> 6, wm = w >> 1, wn = w & 1;
  const int n0 = blockIdx.x * 128;
  f32x4 acc[4][4] = {};
  for (int k0 = 0; k0 < 4 * DD; k0 += 32) {
    stage_bf16(As, mB + k0, 4 * DD, tid);
    {
      const int dcc = tid & 7, er = tid >> 3;
#pragma unroll
      for (int i = 0; i < 4; ++i) {
        int nch = dcc + i * 8;
        float4 v = *(const float4*)(Wm + (long)(k0 + er) * MM + n0 + nch * 4);
        float vv[4] = {v.x, v.y, v.z, v.w};
#pragma unroll
        for (int q = 0; q < 4; ++q)
          Bs[ldsoff(nch * 4 + q, er >> 3) + (er & 7)] = f2bfu(vv[q]);
      }
    }
    __syncthreads();
    mma_step(As, Bs, acc, wm, wn, lane);
    __syncthreads();
  }
  const int lm = lane & 15, quad = lane >> 4;
#pragma unroll
  for (int i = 0; i < 4; ++i)
#pragma unroll
    for (int j = 0; j < 4; ++j) {
      int col = n0 + wn * 64 + j * 16 + lm;
      float bias = bm[col];
#pragma unroll
      for (int r = 0; r < 4; ++r) {
        int row = wm * 64 + i * 16 + quad * 4 + r;
        float v = acc[i][j][r] + bias;
        h[(long)row * MM + col] = v > 0.f ? v : 0.f;
      }
    }
}

// ---- out = h @ Wo + bo ----
__global__ void out3_kernel(const float* __restrict__ h, const float* __restrict__ Wo,
                            const float* __restrict__ bo, float* __restrict__ out) {
  const int b = blockIdx.x, tid = threadIdx.x;
  __shared__ float red[256];
  float a[3] = {0.f, 0.f, 0.f};
  for (int k = tid; k < MM; k += 256) {
    float hv = h[(long)b * MM + k];
    a[0] += hv * Wo[k * 3 + 0];
    a[1] += hv * Wo[k * 3 + 1];
    a[2] += hv * Wo[k * 3 + 2];
  }
#pragma unroll
  for (int o = 0; o < 3; ++o) {
    red[tid] = a[o]; __syncthreads();
    for (int st = 128; st > 0; st >>= 1) {
      if (tid < st) red[tid] += red[tid + st];
      __syncthreads();
    }
    if (tid == 0) out[b * 3 + o] = red[0] + bo[o];
    __syncthreads();
  }
}

extern "C" void kernel_launch(void* const* d_in, const int* in_sizes, int n_in,
                              void* d_out, int out_size, void* d_ws, size_t ws_size,
                              hipStream_t stream) {
  const float* criteria = (const float*)d_in[0];
  const float* ehr      = (const float*)d_in[1];
  const int*   cmask    = (const int*)d_in[2];
  const int*   emask    = (const int*)d_in[3];
  const float* Wa       = (const float*)d_in[4];
  const float* ba       = (const float*)d_in[5];
  const float* Wr       = (const float*)d_in[6];
  const float* br       = (const float*)d_in[7];
  const float* Wm       = (const float*)d_in[8];
  const float* bm       = (const float*)d_in[9];
  const float* Wo       = (const float*)d_in[10];
  const float* bo       = (const float*)d_in[11];
  float* out = (float*)d_out;

  char* ws = (char*)d_ws;
  unsigned short* cB     = (unsigned short*)(ws);
  unsigned short* eB     = (unsigned short*)(ws + 16777216);
  unsigned short* alignB = (unsigned short*)(ws + 83886080);
  unsigned short* ehrT   = (unsigned short*)(ws + 150994944);
  unsigned short* critT  = (unsigned short*)(ws + 218103808);
  float* asum = (float*)(ws + 234881024);
  float* bsum = (float*)(ws + 235143168);
  float* r1   = (float*)(ws + 236191744);
  float* r2   = (float*)(ws + 236322816);
  unsigned short* WaT = (unsigned short*)(ws + 236453888);
  unsigned short* WrT = (unsigned short*)(ws + 236584960);
  unsigned short* mB  = (unsigned short*)(ws + 236847104);
  float* hbuf         = (float*)(ws + 237109248);
  // end: 237,371,392 bytes
  unsigned short* betaT = eB;       // reuse after align
  unsigned short* attc  = cB;       // reuse after align
  unsigned short* atteP = alignB;   // reuse after attc

  dim3 blk(256);
  zero_kernel<<<dim3(256), blk, 0, stream>>>(r1, 2 * BB * DD);
  wconv_kernel<<<dim3(512), blk, 0, stream>>>(Wa, Wr, WaT, WrT);
  transT_kernel<<<dim3(DD / 64, LE / 64, BB), blk, 0, stream>>>(ehr, ehrT, LE, DD);
  transT_kernel<<<dim3(DD / 64, LC / 64, BB), blk, 0, stream>>>(criteria, critT, LC, DD);
  proj_mfma<<<dim3(2, (BB * LC) / 128), blk, 0, stream>>>(criteria, WaT, ba, cB);
  proj_mfma<<<dim3(2, (BB * LE) / 128), blk, 0, stream>>>(ehr, WaT, ba, eB);
  align_mfma<<<dim3(LE / 128, LC / 128, BB), blk, 0, stream>>>(cB, eB, alignB);
  astats_kernel<<<dim3(LC, BB), blk, 0, stream>>>(alignB, emask, asum);
  bstats_kernel<<<dim3(LE / 256, BB), blk, 0, stream>>>(alignB, cmask, bsum);
  betask_kernel<<<dim3(LE / 64, LC / 64, BB), blk, 0, stream>>>(alignB, cmask, bsum, betaT);
  alphask_kernel<<<dim3(16384), blk, 0, stream>>>(alignB, emask, asum);
  attc_mfma<<<dim3(DD / 128, LC / 128, BB), blk, 0, stream>>>(alignB, ehrT, attc);
  atte_mfma<<<dim3(DD / 128, LE / 128, BB), blk, 0, stream>>>(betaT, critT, atteP);
  rsum_mfma<<<dim3(2, (BB * LC) / 128), blk, 0, stream>>>(attc, criteria, WrT, br, r1, LC);
  rsum_mfma<<<dim3(2, (BB * LE) / 128), blk, 0, stream>>>(atteP, ehr, WrT, br, r2, LE);
  mbuild_kernel<<<dim3(BB), blk, 0, stream>>>(r1, r2, mB);
  mlp_mfma<<<dim3(MM / 128), blk, 0, stream>>>(mB, Wm, bm, hbuf);
  out3_kernel<<<dim3(BB), blk, 0, stream>>>(hbuf, Wo, bo, out);
}

// Round 6
// 626.378 us; speedup vs baseline: 1.2108x; 1.0834x over previous
//
#include <hip/hip_runtime.h>
#include <hip/hip_bf16.h>

#define BB 128
#define LC 256
#define LE 1024
#define DD 256
#define MM 512

typedef short bf16x8 __attribute__((ext_vector_type(8)));
typedef unsigned short u16x8 __attribute__((ext_vector_type(8)));
typedef unsigned short u16x4 __attribute__((ext_vector_type(4)));
typedef float f32x4 __attribute__((ext_vector_type(4)));

__device__ __forceinline__ float bfu2f(unsigned short u) {
  return __uint_as_float(((unsigned int)u) << 16);
}
__device__ __forceinline__ unsigned short f2bfu(float f) {
  unsigned int x = __float_as_uint(f);
  return (unsigned short)((x + 0x7fffu + ((x >> 16) & 1u)) >> 16);
}

// LDS tile: 128 rows x 32 k (u16), row stride 40, 16B-chunk XOR swizzle.
#define LDST 40
__device__ __forceinline__ int ldsoff(int r, int q) {
  return r * LDST + ((q ^ ((r >> 2) & 3)) << 3);
}

// ---- shared MFMA inner step: 4 waves, each 64x64 = 4x4 tiles of 16x16x32 ----
__device__ __forceinline__ void mma_step(const unsigned short* As, const unsigned short* Bs,
                                         f32x4 (&acc)[4][4], int wm, int wn, int lane) {
  const int lm = lane & 15, quad = lane >> 4;
  bf16x8 a[4], b[4];
#pragma unroll
  for (int i = 0; i < 4; ++i) {
    int r = wm * 64 + i * 16 + lm;
    a[i] = *(const bf16x8*)&As[ldsoff(r, quad)];
    int n = wn * 64 + i * 16 + lm;
    b[i] = *(const bf16x8*)&Bs[ldsoff(n, quad)];
  }
#pragma unroll
  for (int i = 0; i < 4; ++i)
#pragma unroll
    for (int j = 0; j < 4; ++j)
      acc[i][j] = __builtin_amdgcn_mfma_f32_16x16x32_bf16(a[i], b[j], acc[i][j], 0, 0, 0);
}

// ---- natural staging: bf16 source rows [r][k], 128x32 tile ----
__device__ __forceinline__ void stage_bf16(unsigned short* S, const unsigned short* g,
                                           long ld, int tid) {
#pragma unroll
  for (int i = 0; i < 2; ++i) {
    int c = tid + i * 256;
    int r = c >> 2, q = c & 3;
    u16x8 v = *(const u16x8*)(g + (long)r * ld + q * 8);
    *(u16x8*)&S[ldsoff(r, q)] = v;
  }
}

// ---- natural staging with fp32 -> bf16 convert ----
__device__ __forceinline__ void stage_f32(unsigned short* S, const float* g, long ld, int tid) {
#pragma unroll
  for (int i = 0; i < 2; ++i) {
    int c = tid + i * 256;
    int r = c >> 2, q = c & 3;
    const float4* p = (const float4*)(g + (long)r * ld + q * 8);
    float4 v0 = p[0], v1 = p[1];
    u16x8 o;
    o[0] = f2bfu(v0.x); o[1] = f2bfu(v0.y); o[2] = f2bfu(v0.z); o[3] = f2bfu(v0.w);
    o[4] = f2bfu(v1.x); o[5] = f2bfu(v1.y); o[6] = f2bfu(v1.z); o[7] = f2bfu(v1.w);
    *(u16x8*)&S[ldsoff(r, q)] = o;
  }
}

// ---- zero fill ----
__global__ void zero_kernel(float* __restrict__ p, int n) {
  int i = blockIdx.x * 256 + threadIdx.x;
  if (i < n) p[i] = 0.f;
}

// ---- weight transpose+convert ----
__global__ void wconv_kernel(const float* __restrict__ Wa, const float* __restrict__ Wr,
                             unsigned short* __restrict__ WaT, unsigned short* __restrict__ WrT) {
  int i = blockIdx.x * 256 + threadIdx.x;
  if (i < 65536) WaT[i] = f2bfu(Wa[(i & 255) * 256 + (i >> 8)]);
  if (i < 131072) WrT[i] = f2bfu(Wr[(long)(i & 511) * 256 + (i >> 9)]);
}

// ---- fp32 [R][C] -> (a) mask-baked bf16 transpose dstT[C][R], (b) natural bf16 dstN[R][C] ----
__global__ void transT_kernel(const float* __restrict__ src, const int* __restrict__ mask,
                              unsigned short* __restrict__ dstT, unsigned short* __restrict__ dstN,
                              int R, int C) {
  __shared__ unsigned short T[64][72];
  const int tid = threadIdx.x, b = blockIdx.z;
  const int r0 = blockIdx.y * 64, c0 = blockIdx.x * 64;
  const float* s = src + (long)b * R * C;
  const int* mk = mask + (long)b * R;
  unsigned short* dT = dstT + (long)b * R * C;
  unsigned short* dN = dstN + (long)b * R * C;
#pragma unroll
  for (int i = 0; i < 4; ++i) {
    int r = (tid >> 4) + i * 16, c4 = tid & 15;
    float4 v = *(const float4*)(s + (long)(r0 + r) * C + c0 + c4 * 4);
    u16x4 nat;
    nat[0] = f2bfu(v.x); nat[1] = f2bfu(v.y); nat[2] = f2bfu(v.z); nat[3] = f2bfu(v.w);
    *(u16x4*)(dN + (long)(r0 + r) * C + c0 + c4 * 4) = nat;
    float g = mk[r0 + r] ? 1.f : 0.f;
    T[c4 * 4 + 0][r] = f2bfu(v.x * g);
    T[c4 * 4 + 1][r] = f2bfu(v.y * g);
    T[c4 * 4 + 2][r] = f2bfu(v.z * g);
    T[c4 * 4 + 3][r] = f2bfu(v.w * g);
  }
  __syncthreads();
#pragma unroll
  for (int j = 0; j < 2; ++j) {
    int idx = tid * 2 + j;
    int row = idx >> 3, ch = idx & 7;
    *(u16x8*)(dT + (long)(c0 + row) * R + r0 + ch * 8) = *(const u16x8*)&T[row][ch * 8];
  }
}

// ---- proj: out = relu(A @ Wa + ba) -> bf16 ----
__global__ __launch_bounds__(256, 2) void proj_mfma(const float* __restrict__ A,
                                                    const unsigned short* __restrict__ WaT,
                                                    const float* __restrict__ ba,
                                                    unsigned short* __restrict__ out) {
  __shared__ unsigned short As[128 * LDST], Bs[128 * LDST];
  const int tid = threadIdx.x, lane = tid & 63, w = tid >> 6, wm = w >> 1, wn = w & 1;
  const long m0 = (long)blockIdx.y * 128;
  const int n0 = blockIdx.x * 128;
  f32x4 acc[4][4] = {};
  for (int k0 = 0; k0 < DD; k0 += 32) {
    stage_f32(As, A + m0 * DD + k0, DD, tid);
    stage_bf16(Bs, WaT + (long)n0 * DD + k0, DD, tid);
    __syncthreads();
    mma_step(As, Bs, acc, wm, wn, lane);
    __syncthreads();
  }
  const int lm = lane & 15, quad = lane >> 4;
#pragma unroll
  for (int i = 0; i < 4; ++i)
#pragma unroll
    for (int j = 0; j < 4; ++j) {
      int col = n0 + wn * 64 + j * 16 + lm;
      float bias = ba[col];
#pragma unroll
      for (int r = 0; r < 4; ++r) {
        long row = m0 + wm * 64 + i * 16 + quad * 4 + r;
        float v = acc[i][j][r] + bias;
        out[row * DD + col] = f2bfu(v > 0.f ? v : 0.f);
      }
    }
}

// ---- align fused: expv = exp(c.e), write natural + transposed, accumulate asum/bsum ----
__global__ __launch_bounds__(256, 2) void align_fused(
    const unsigned short* __restrict__ cB, const unsigned short* __restrict__ eB,
    const int* __restrict__ em, const int* __restrict__ cm,
    unsigned short* __restrict__ expv, unsigned short* __restrict__ expvT,
    float* __restrict__ asum, float* __restrict__ bsum) {
  __shared__ unsigned short As[128 * LDST], Bs[128 * LDST];
  __shared__ float asum_s[128], bsum_s[128];
  const int tid = threadIdx.x, lane = tid & 63, w = tid >> 6, wm = w >> 1, wn = w & 1;
  const int b = blockIdx.z, m0 = blockIdx.y * 128, n0 = blockIdx.x * 128;
  const unsigned short* Ag = cB + ((long)b * LC + m0) * DD;
  const unsigned short* Bg = eB + ((long)b * LE + n0) * DD;
  f32x4 acc[4][4] = {};
  for (int k0 = 0; k0 < DD; k0 += 32) {
    stage_bf16(As, Ag + k0, DD, tid);
    stage_bf16(Bs, Bg + k0, DD, tid);
    __syncthreads();
    mma_step(As, Bs, acc, wm, wn, lane);
    __syncthreads();
  }
  if (tid < 128) { asum_s[tid] = 0.f; bsum_s[tid] = 0.f; }
  __syncthreads();
  const int lm = lane & 15, quad = lane >> 4;
  float emv[4], cmv[4][4];
#pragma unroll
  for (int j = 0; j < 4; ++j)
    emv[j] = em[b * LE + n0 + wn * 64 + j * 16 + lm] ? 1.f : 0.f;
#pragma unroll
  for (int i = 0; i < 4; ++i)
#pragma unroll
    for (int r = 0; r < 4; ++r)
      cmv[i][r] = cm[b * LC + m0 + wm * 64 + i * 16 + quad * 4 + r] ? 1.f : 0.f;
  // exp in place + dual-layout write
#pragma unroll
  for (int i = 0; i < 4; ++i)
#pragma unroll
    for (int j = 0; j < 4; ++j) {
      int col = n0 + wn * 64 + j * 16 + lm;
      int lrow0 = m0 + wm * 64 + i * 16 + quad * 4;
      u16x4 tv;
#pragma unroll
      for (int r = 0; r < 4; ++r) {
        float e_ = __expf(acc[i][j][r]);
        acc[i][j][r] = e_;
        unsigned short bv = f2bfu(e_);
        expv[((long)b * LC + lrow0 + r) * LE + col] = bv;
        tv[r] = bv;
      }
      *(u16x4*)&expvT[((long)b * LE + col) * LC + lrow0] = tv;
    }
  // asum partials: per row, sum em*ev over this wave's 64 cols
#pragma unroll
  for (int i = 0; i < 4; ++i)
#pragma unroll
    for (int r = 0; r < 4; ++r) {
      float s = emv[0] * acc[i][0][r] + emv[1] * acc[i][1][r] +
                emv[2] * acc[i][2][r] + emv[3] * acc[i][3][r];
      s += __shfl_xor(s, 1); s += __shfl_xor(s, 2);
      s += __shfl_xor(s, 4); s += __shfl_xor(s, 8);
      if (lm == 0) atomicAdd(&asum_s[wm * 64 + i * 16 + quad * 4 + r], s);
    }
  // bsum partials: per col, sum cm*ev over this wave's 64 rows
#pragma unroll
  for (int j = 0; j < 4; ++j) {
    float t = 0.f;
#pragma unroll
    for (int i = 0; i < 4; ++i)
#pragma unroll
      for (int r = 0; r < 4; ++r) t += cmv[i][r] * acc[i][j][r];
    t += __shfl_xor(t, 16); t += __shfl_xor(t, 32);
    if (quad == 0) atomicAdd(&bsum_s[wn * 64 + j * 16 + lm], t);
  }
  __syncthreads();
  if (tid < 128) {
    atomicAdd(&asum[b * LC + m0 + tid], asum_s[tid]);
    atomicAdd(&bsum[b * LE + n0 + tid], bsum_s[tid]);
  }
}

// ---- attc = (expv @ ehrTm^T) * (1/asum[row]) ----
__global__ __launch_bounds__(256, 2) void attc_mfma(const unsigned short* __restrict__ expv,
                                                    const unsigned short* __restrict__ ehrTm,
                                                    const float* __restrict__ asum,
                                                    unsigned short* __restrict__ attc) {
  __shared__ unsigned short As[128 * LDST], Bs[128 * LDST];
  const int tid = threadIdx.x, lane = tid & 63, w = tid >> 6, wm = w >> 1, wn = w & 1;
  const int b = blockIdx.z, m0 = blockIdx.y * 128, n0 = blockIdx.x * 128;
  const unsigned short* Ag = expv + ((long)b * LC + m0) * LE;
  const unsigned short* Bg = ehrTm + ((long)b * DD + n0) * LE;
  f32x4 acc[4][4] = {};
  for (int k0 = 0; k0 < LE; k0 += 32) {
    stage_bf16(As, Ag + k0, LE, tid);
    stage_bf16(Bs, Bg + k0, LE, tid);
    __syncthreads();
    mma_step(As, Bs, acc, wm, wn, lane);
    __syncthreads();
  }
  const int lm = lane & 15, quad = lane >> 4;
  float rs[4][4];
#pragma unroll
  for (int i = 0; i < 4; ++i)
#pragma unroll
    for (int r = 0; r < 4; ++r)
      rs[i][r] = 1.f / asum[b * LC + m0 + wm * 64 + i * 16 + quad * 4 + r];
#pragma unroll
  for (int i = 0; i < 4; ++i)
#pragma unroll
    for (int j = 0; j < 4; ++j) {
      int col = n0 + wn * 64 + j * 16 + lm;
#pragma unroll
      for (int r = 0; r < 4; ++r) {
        int row = m0 + wm * 64 + i * 16 + quad * 4 + r;
        attc[((long)b * LC + row) * DD + col] = f2bfu(acc[i][j][r] * rs[i][r]);
      }
    }
}

// ---- atte = (expvT @ critTm^T) * (1/bsum[row]) ----
__global__ __launch_bounds__(256, 2) void atte_mfma(const unsigned short* __restrict__ expvT,
                                                    const unsigned short* __restrict__ critTm,
                                                    const float* __restrict__ bsum,
                                                    unsigned short* __restrict__ atte) {
  __shared__ unsigned short As[128 * LDST], Bs[128 * LDST];
  const int tid = threadIdx.x, lane = tid & 63, w = tid >> 6, wm = w >> 1, wn = w & 1;
  const int b = blockIdx.z, m0 = blockIdx.y * 128, n0 = blockIdx.x * 128;
  const unsigned short* Ag = expvT + ((long)b * LE + m0) * LC;
  const unsigned short* Bg = critTm + ((long)b * DD + n0) * LC;
  f32x4 acc[4][4] = {};
  for (int k0 = 0; k0 < LC; k0 += 32) {
    stage_bf16(As, Ag + k0, LC, tid);
    stage_bf16(Bs, Bg + k0, LC, tid);
    __syncthreads();
    mma_step(As, Bs, acc, wm, wn, lane);
    __syncthreads();
  }
  const int lm = lane & 15, quad = lane >> 4;
  float rs[4][4];
#pragma unroll
  for (int i = 0; i < 4; ++i)
#pragma unroll
    for (int r = 0; r < 4; ++r)
      rs[i][r] = 1.f / bsum[b * LE + m0 + wm * 64 + i * 16 + quad * 4 + r];
#pragma unroll
  for (int i = 0; i < 4; ++i)
#pragma unroll
    for (int j = 0; j < 4; ++j) {
      int col = n0 + wn * 64 + j * 16 + lm;
#pragma unroll
      for (int r = 0; r < 4; ++r) {
        int row = m0 + wm * 64 + i * 16 + quad * 4 + r;
        atte[((long)b * LE + row) * DD + col] = f2bfu(acc[i][j][r] * rs[i][r]);
      }
    }
}

// ---- r = sum_seq relu([att | origB] @ Wr + br), all-bf16 staging ----
__global__ __launch_bounds__(256, 2) void rsum_mfma(const unsigned short* __restrict__ att,
                                                    const unsigned short* __restrict__ origB,
                                                    const unsigned short* __restrict__ WrT,
                                                    const float* __restrict__ br,
                                                    float* __restrict__ rout, int Lseq) {
  __shared__ unsigned short As[128 * LDST], Bs[128 * LDST];
  __shared__ float red[2][128];
  const int tid = threadIdx.x, lane = tid & 63, w = tid >> 6, wm = w >> 1, wn = w & 1;
  const long m0 = (long)blockIdx.y * 128;
  const int n0 = blockIdx.x * 128;
  const int b = (int)(m0 / Lseq);
  f32x4 acc[4][4] = {};
  for (int k0 = 0; k0 < 2 * DD; k0 += 32) {
    if (k0 < DD)
      stage_bf16(As, att + m0 * DD + k0, DD, tid);
    else
      stage_bf16(As, origB + m0 * DD + (k0 - DD), DD, tid);
    stage_bf16(Bs, WrT + (long)n0 * (2 * DD) + k0, 2 * DD, tid);
    __syncthreads();
    mma_step(As, Bs, acc, wm, wn, lane);
    __syncthreads();
  }
  const int lm = lane & 15, quad = lane >> 4;
#pragma unroll
  for (int j = 0; j < 4; ++j) {
    int col = n0 + wn * 64 + j * 16 + lm;
    float bias = br[col];
    float s = 0.f;
#pragma unroll
    for (int i = 0; i < 4; ++i)
#pragma unroll
      for (int r = 0; r < 4; ++r) {
        float v = acc[i][j][r] + bias;
        s += v > 0.f ? v : 0.f;
      }
    s += __shfl_xor(s, 16);
    s += __shfl_xor(s, 32);
    if (quad == 0) red[wm][wn * 64 + j * 16 + lm] = s;
  }
  __syncthreads();
  if (tid < 128)
    atomicAdd(&rout[b * DD + n0 + tid], red[0][tid] + red[1][tid]);
}

// ---- build m = [r1 | r2 | r1*r2 | r1-r2] as bf16 [128][1024] ----
__global__ void mbuild_kernel(const float* __restrict__ r1, const float* __restrict__ r2,
                              unsigned short* __restrict__ mB) {
  int i = blockIdx.x * 256 + threadIdx.x;
  int b = i >> 8, d = i & 255;
  float v1 = r1[i], v2 = r2[i];
  unsigned short* row = mB + (long)b * 1024;
  row[d] = f2bfu(v1);
  row[256 + d] = f2bfu(v2);
  row[512 + d] = f2bfu(v1 * v2);
  row[768 + d] = f2bfu(v1 - v2);
}

// ---- h = relu(m @ Wm + bm): M=128, N=512, K=1024 MFMA GEMM ----
__global__ __launch_bounds__(256, 2) void mlp_mfma(const unsigned short* __restrict__ mB,
                                                   const float* __restrict__ Wm,
                                                   const float* __restrict__ bm,
                                                   float* __restrict__ h) {
  __shared__ unsigned short As[128 * LDST], Bs[128 * LDST];
  const int tid = threadIdx.x, lane = tid & 63, w = tid >> 6, wm = w >> 1, wn = w & 1;
  const int n0 = blockIdx.x * 128;
  f32x4 acc[4][4] = {};
  for (int k0 = 0; k0 < 4 * DD; k0 += 32) {
    stage_bf16(As, mB + k0, 4 * DD, tid);
    {
      const int dcc = tid & 7, er = tid >> 3;
#pragma unroll
      for (int i = 0; i < 4; ++i) {
        int nch = dcc + i * 8;
        float4 v = *(const float4*)(Wm + (long)(k0 + er) * MM + n0 + nch * 4);
        float vv[4] = {v.x, v.y, v.z, v.w};
#pragma unroll
        for (int q = 0; q < 4; ++q)
          Bs[ldsoff(nch * 4 + q, er >> 3) + (er & 7)] = f2bfu(vv[q]);
      }
    }
    __syncthreads();
    mma_step(As, Bs, acc, wm, wn, lane);
    __syncthreads();
  }
  const int lm = lane & 15, quad = lane >> 4;
#pragma unroll
  for (int i = 0; i < 4; ++i)
#pragma unroll
    for (int j = 0; j < 4; ++j) {
      int col = n0 + wn * 64 + j * 16 + lm;
      float bias = bm[col];
#pragma unroll
      for (int r = 0; r < 4; ++r) {
        int row = wm * 64 + i * 16 + quad * 4 + r;
        float v = acc[i][j][r] + bias;
        h[(long)row * MM + col] = v > 0.f ? v : 0.f;
      }
    }
}

// ---- out = h @ Wo + bo ----
__global__ void out3_kernel(const float* __restrict__ h, const float* __restrict__ Wo,
                            const float* __restrict__ bo, float* __restrict__ out) {
  const int b = blockIdx.x, tid = threadIdx.x;
  __shared__ float red[256];
  float a[3] = {0.f, 0.f, 0.f};
  for (int k = tid; k < MM; k += 256) {
    float hv = h[(long)b * MM + k];
    a[0] += hv * Wo[k * 3 + 0];
    a[1] += hv * Wo[k * 3 + 1];
    a[2] += hv * Wo[k * 3 + 2];
  }
#pragma unroll
  for (int o = 0; o < 3; ++o) {
    red[tid] = a[o]; __syncthreads();
    for (int st = 128; st > 0; st >>= 1) {
      if (tid < st) red[tid] += red[tid + st];
      __syncthreads();
    }
    if (tid == 0) out[b * 3 + o] = red[0] + bo[o];
    __syncthreads();
  }
}

extern "C" void kernel_launch(void* const* d_in, const int* in_sizes, int n_in,
                              void* d_out, int out_size, void* d_ws, size_t ws_size,
                              hipStream_t stream) {
  const float* criteria = (const float*)d_in[0];
  const float* ehr      = (const float*)d_in[1];
  const int*   cmask    = (const int*)d_in[2];
  const int*   emask    = (const int*)d_in[3];
  const float* Wa       = (const float*)d_in[4];
  const float* ba       = (const float*)d_in[5];
  const float* Wr       = (const float*)d_in[6];
  const float* br       = (const float*)d_in[7];
  const float* Wm       = (const float*)d_in[8];
  const float* bm       = (const float*)d_in[9];
  const float* Wo       = (const float*)d_in[10];
  const float* bo       = (const float*)d_in[11];
  float* out = (float*)d_out;

  char* ws = (char*)d_ws;
  // Buffer choreography (387.7 MB of the 512 MB workspace):
  unsigned short* cB     = (unsigned short*)(ws);               // 16.78 MB; attc out after align
  unsigned short* eB     = (unsigned short*)(ws + 16777216);    // 67.1 MB; dead after align
  unsigned short* alignB = (unsigned short*)(ws + 83886080);    // 67.1 MB expv; atte out after attc
  unsigned short* ehrTm  = (unsigned short*)(ws + 150994944);   // 67.1 MB, em-masked ehr^T
  unsigned short* critTm = (unsigned short*)(ws + 218103808);   // 16.78 MB, cm-masked crit^T
  unsigned short* expvT  = (unsigned short*)(ws + 234881024);   // 67.1 MB
  unsigned short* ehrN   = (unsigned short*)(ws + 301989888);   // 67.1 MB natural bf16 ehr
  unsigned short* critN  = (unsigned short*)(ws + 369098752);   // 16.78 MB natural bf16 crit
  float* asum = (float*)(ws + 385875968);                       // 131072 B
  float* bsum = (float*)(ws + 386007040);                       // 524288 B
  float* r1   = (float*)(ws + 386531328);                       // 131072 B
  float* r2   = (float*)(ws + 386662400);                       // 131072 B
  unsigned short* WaT = (unsigned short*)(ws + 386793472);
  unsigned short* WrT = (unsigned short*)(ws + 386924544);
  unsigned short* mB  = (unsigned short*)(ws + 387186688);
  float* hbuf         = (float*)(ws + 387448832);
  // end: 387,710,976 bytes
  unsigned short* attc  = cB;      // reuse (dead after align_fused)
  unsigned short* atteP = alignB;  // reuse (dead after attc)

  dim3 blk(256);
  // zero asum+bsum+r1+r2 (contiguous, 229376 floats)
  zero_kernel<<<dim3(896), blk, 0, stream>>>(asum, 229376);
  wconv_kernel<<<dim3(512), blk, 0, stream>>>(Wa, Wr, WaT, WrT);
  transT_kernel<<<dim3(DD / 64, LE / 64, BB), blk, 0, stream>>>(ehr, emask, ehrTm, ehrN, LE, DD);
  transT_kernel<<<dim3(DD / 64, LC / 64, BB), blk, 0, stream>>>(criteria, cmask, critTm, critN, LC, DD);
  proj_mfma<<<dim3(2, (BB * LC) / 128), blk, 0, stream>>>(criteria, WaT, ba, cB);
  proj_mfma<<<dim3(2, (BB * LE) / 128), blk, 0, stream>>>(ehr, WaT, ba, eB);
  align_fused<<<dim3(LE / 128, LC / 128, BB), blk, 0, stream>>>(cB, eB, emask, cmask,
                                                                alignB, expvT, asum, bsum);
  attc_mfma<<<dim3(DD / 128, LC / 128, BB), blk, 0, stream>>>(alignB, ehrTm, asum, attc);
  atte_mfma<<<dim3(DD / 128, LE / 128, BB), blk, 0, stream>>>(expvT, critTm, bsum, atteP);
  rsum_mfma<<<dim3(2, (BB * LC) / 128), blk, 0, stream>>>(attc, critN, WrT, br, r1, LC);
  rsum_mfma<<<dim3(2, (BB * LE) / 128), blk, 0, stream>>>(atteP, ehrN, WrT, br, r2, LE);
  mbuild_kernel<<<dim3(BB), blk, 0, stream>>>(r1, r2, mB);
  mlp_mfma<<<dim3(MM / 128), blk, 0, stream>>>(mB, Wm, bm, hbuf);
  out3_kernel<<<dim3(BB), blk, 0, stream>>>(hbuf, Wo, bo, out);
}